// Round 1
// baseline (15407.387 us; speedup 1.0000x reference)
//
#include <hip/hip_runtime.h>
#include <math.h>

#define NNODES 100000

__device__ __forceinline__ void atomAddF(float* p, float v) {
#if defined(__gfx90a__) || defined(__gfx940__) || defined(__gfx941__) || defined(__gfx942__) || defined(__gfx950__)
    unsafeAtomicAdd(p, v);
#else
    atomicAdd(p, v);
#endif
}

// ---------------- node projections: Q,K,V,S = X@W + b -------------------
template<int CIN, int HC>
__global__ void proj_kernel(const float* __restrict__ X,
                            const float* __restrict__ wq, const float* __restrict__ bq,
                            const float* __restrict__ wk, const float* __restrict__ bk,
                            const float* __restrict__ wv, const float* __restrict__ bv,
                            const float* __restrict__ wsk, const float* __restrict__ bsk,
                            float* __restrict__ Q, float* __restrict__ K,
                            float* __restrict__ V, float* __restrict__ S, int N)
{
    int idx = blockIdx.x * blockDim.x + threadIdx.x;
    if (idx >= N * HC) return;
    int n = idx / HC;
    int c = idx - n * HC;
    float q = bq[c], k = bk[c], v = bv[c], s = bsk[c];
    const float* xr = X + (long long)n * CIN;
#pragma unroll
    for (int i = 0; i < CIN; ++i) {
        float xi = xr[i];
        q = fmaf(xi, wq[i * HC + c], q);
        k = fmaf(xi, wk[i * HC + c], k);
        v = fmaf(xi, wv[i * HC + c], v);
        s = fmaf(xi, wsk[i * HC + c], s);
    }
    Q[idx] = q; K[idx] = k; V[idx] = v; S[idx] = s;
}

// ---------------- edge pass: one thread per (edge, head) ----------------
// Accumulates NUM[dst] += exp(logit)*(V[src]+e), DEN[dst] += exp(logit).
template<int H, int C>
__global__ void edge_kernel(const int* __restrict__ ei, const float* __restrict__ ea,
                            const float* __restrict__ we,
                            const float* __restrict__ Q, const float* __restrict__ K,
                            const float* __restrict__ V,
                            float* __restrict__ NUM, float* __restrict__ DEN,
                            int E, float scale)
{
    const int HC = H * C;
    int tid = blockIdx.x * blockDim.x + threadIdx.x;
    if (tid >= E * H) return;
    int e = tid / H;
    int h = tid - e * H;
    int src = ei[e];
    int dst = ei[E + e];

    float a[8];
    const float* eap = ea + (long long)e * 8;
#pragma unroll
    for (int d = 0; d < 8; ++d) a[d] = eap[d];

    const float* weh = we + h * C;            // we[d*HC + h*C + i]
    const float* Qp  = Q + (long long)dst * HC + h * C;
    const float* Kp  = K + (long long)src * HC + h * C;
    const float* Vp  = V + (long long)src * HC + h * C;

    float dot = 0.f;
#pragma unroll
    for (int i = 0; i < C; ++i) {
        float ec = 0.f;
#pragma unroll
        for (int d = 0; d < 8; ++d) ec = fmaf(a[d], weh[d * HC + i], ec);
        dot = fmaf(Qp[i], Kp[i] + ec, dot);
    }
    float ex = expf(dot * scale);
    atomAddF(&DEN[(long long)dst * H + h], ex);

    float* np_ = NUM + (long long)dst * HC + h * C;
#pragma unroll
    for (int i = 0; i < C; ++i) {
        float ec = 0.f;
#pragma unroll
        for (int d = 0; d < 8; ++d) ec = fmaf(a[d], weh[d * HC + i], ec);
        atomAddF(&np_[i], ex * (Vp[i] + ec));
    }
}

// ---------------- finalize: one wave (64 lanes) per node ----------------
// out = NUM/(DEN+eps); g = sigmoid([out, s, out-s]@wbeta); h = relu(g*s+(1-g)*out)
// FINAL: also reduce h@wc + bc -> OUT[n] (scalar per node).
template<int H, int C, bool FINAL>
__global__ void finalize_kernel(const float* __restrict__ NUM, const float* __restrict__ DEN,
                                const float* __restrict__ S,
                                const float* __restrict__ wb,
                                const float* __restrict__ wc, const float* __restrict__ bc,
                                float* __restrict__ OUT, int N)
{
    const int HC = H * C;
    int wid = (blockIdx.x * blockDim.x + threadIdx.x) >> 6;
    int lane = threadIdx.x & 63;
    if (wid >= N) return;

    float outc = 0.f, sc = 0.f, gd = 0.f;
    if (lane < HC) {
        float num = NUM[(long long)wid * HC + lane];
        float den = DEN[(long long)wid * H + lane / C];
        outc = num / (den + 1e-16f);
        sc = S[(long long)wid * HC + lane];
        gd = outc * wb[lane] + sc * wb[HC + lane] + (outc - sc) * wb[2 * HC + lane];
    }
#pragma unroll
    for (int off = 32; off > 0; off >>= 1) gd += __shfl_xor(gd, off, 64);
    float g = 1.f / (1.f + expf(-gd));
    float h = g * sc + (1.f - g) * outc;
    h = fmaxf(h, 0.f);
    if (FINAL) {
        float t = (lane < HC) ? h * wc[lane] : 0.f;
#pragma unroll
        for (int off = 32; off > 0; off >>= 1) t += __shfl_xor(t, off, 64);
        if (lane == 0) OUT[wid] = t + bc[0];
    } else {
        if (lane < HC) OUT[(long long)wid * HC + lane] = h;
    }
}

extern "C" void kernel_launch(void* const* d_in, const int* in_sizes, int n_in,
                              void* d_out, int out_size, void* d_ws, size_t ws_size,
                              hipStream_t stream) {
    const float* x  = (const float*)d_in[0];
    const int*   ei = (const int*)d_in[1];
    const float* ea = (const float*)d_in[2];
    const int N = in_sizes[0] / 32;
    const int E = in_sizes[1] / 2;

    int p = 3;
    const float *wq1=(const float*)d_in[p+0], *bq1=(const float*)d_in[p+1],
                *wk1=(const float*)d_in[p+2], *bk1=(const float*)d_in[p+3],
                *wv1=(const float*)d_in[p+4], *bv1=(const float*)d_in[p+5],
                *we1=(const float*)d_in[p+6],
                *wsk1=(const float*)d_in[p+7], *bsk1=(const float*)d_in[p+8],
                *wb1=(const float*)d_in[p+9];
    p += 10;
    const float *wq2=(const float*)d_in[p+0], *bq2=(const float*)d_in[p+1],
                *wk2=(const float*)d_in[p+2], *bk2=(const float*)d_in[p+3],
                *wv2=(const float*)d_in[p+4], *bv2=(const float*)d_in[p+5],
                *we2=(const float*)d_in[p+6],
                *wsk2=(const float*)d_in[p+7], *bsk2=(const float*)d_in[p+8],
                *wb2=(const float*)d_in[p+9];
    p += 10;
    const float *wq3=(const float*)d_in[p+0], *bq3=(const float*)d_in[p+1],
                *wk3=(const float*)d_in[p+2], *bk3=(const float*)d_in[p+3],
                *wv3=(const float*)d_in[p+4], *bv3=(const float*)d_in[p+5],
                *we3=(const float*)d_in[p+6],
                *wsk3=(const float*)d_in[p+7], *bsk3=(const float*)d_in[p+8],
                *wb3=(const float*)d_in[p+9];
    p += 10;
    const float *wc = (const float*)d_in[p+0], *bc = (const float*)d_in[p+1];

    float* out = (float*)d_out;

    // workspace layout (floats), NB = N*64
    size_t NB = (size_t)N * 64;
    float* ws = (float*)d_ws;
    float* A    = ws;            // node buffer / NUM (layers 1,3)
    float* B    = A  + NB;       // node buffer / NUM (layer 2)
    float* Qb   = B  + NB;
    float* Kb   = Qb + NB;
    float* Vb   = Kb + NB;
    float* Sb   = Vb + NB;
    float* DENb = Sb + NB;       // N*8 floats

    const int BLK = 256;

    // ---------------- layer 1: cin=32, H=8, C=6 (HC=48) ----------------
    proj_kernel<32,48><<<(N*48 + BLK-1)/BLK, BLK, 0, stream>>>(
        x, wq1,bq1, wk1,bk1, wv1,bv1, wsk1,bsk1, Qb,Kb,Vb,Sb, N);
    hipMemsetAsync(A,    0, (size_t)N*48*sizeof(float), stream);
    hipMemsetAsync(DENb, 0, (size_t)N*8*sizeof(float),  stream);
    edge_kernel<8,6><<<((size_t)E*8 + BLK-1)/BLK, BLK, 0, stream>>>(
        ei, ea, we1, Qb, Kb, Vb, A, DENb, E, 1.0f/sqrtf(6.0f));
    finalize_kernel<8,6,false><<<(N + 3)/4, BLK, 0, stream>>>(
        A, DENb, Sb, wb1, nullptr, nullptr, A, N);

    // ---------------- layer 2: cin=48, H=8, C=3 (HC=24) ----------------
    proj_kernel<48,24><<<(N*24 + BLK-1)/BLK, BLK, 0, stream>>>(
        A, wq2,bq2, wk2,bk2, wv2,bv2, wsk2,bsk2, Qb,Kb,Vb,Sb, N);
    hipMemsetAsync(B,    0, (size_t)N*24*sizeof(float), stream);
    hipMemsetAsync(DENb, 0, (size_t)N*8*sizeof(float),  stream);
    edge_kernel<8,3><<<((size_t)E*8 + BLK-1)/BLK, BLK, 0, stream>>>(
        ei, ea, we2, Qb, Kb, Vb, B, DENb, E, 1.0f/sqrtf(3.0f));
    finalize_kernel<8,3,false><<<(N + 3)/4, BLK, 0, stream>>>(
        B, DENb, Sb, wb2, nullptr, nullptr, B, N);

    // ---------------- layer 3: cin=24, H=1, C=64 (HC=64) ----------------
    proj_kernel<24,64><<<(N*64 + BLK-1)/BLK, BLK, 0, stream>>>(
        B, wq3,bq3, wk3,bk3, wv3,bv3, wsk3,bsk3, Qb,Kb,Vb,Sb, N);
    hipMemsetAsync(A,    0, (size_t)N*64*sizeof(float), stream);
    hipMemsetAsync(DENb, 0, (size_t)N*1*sizeof(float),  stream);
    edge_kernel<1,64><<<((size_t)E + BLK-1)/BLK, BLK, 0, stream>>>(
        ei, ea, we3, Qb, Kb, Vb, A, DENb, E, 1.0f/8.0f);
    finalize_kernel<1,64,true><<<(N + 3)/4, BLK, 0, stream>>>(
        A, DENb, Sb, wb3, wc, bc, out, N);
}

// Round 2
// 1881.279 us; speedup vs baseline: 8.1898x; 8.1898x over previous
//
#include <hip/hip_runtime.h>
#include <math.h>

#define SCAN_BLK 256

// ---------------- CSR build ----------------
__global__ void count_kernel(const int* __restrict__ ei, int* __restrict__ deg, int E) {
    int e = blockIdx.x * blockDim.x + threadIdx.x;
    if (e < E) atomicAdd(&deg[ei[E + e]], 1);
}

// per-block exclusive scan partials + block sums
__global__ void scan1_kernel(const int* __restrict__ deg, int* __restrict__ part,
                             int* __restrict__ bsum, int N) {
    __shared__ int sm[SCAN_BLK];
    int i = blockIdx.x * SCAN_BLK + threadIdx.x;
    int v = (i < N) ? deg[i] : 0;
    sm[threadIdx.x] = v;
    __syncthreads();
    for (int off = 1; off < SCAN_BLK; off <<= 1) {
        int t = (threadIdx.x >= off) ? sm[threadIdx.x - off] : 0;
        __syncthreads();
        sm[threadIdx.x] += t;
        __syncthreads();
    }
    if (i < N) part[i] = sm[threadIdx.x] - v;     // exclusive within block
    if (threadIdx.x == SCAN_BLK - 1) bsum[blockIdx.x] = sm[threadIdx.x];
}

// single-block exclusive scan of block sums (nb <= 512)
__global__ void scan2_kernel(const int* __restrict__ bsum, int* __restrict__ boff, int nb) {
    __shared__ int sm[512];
    int v = (threadIdx.x < nb) ? bsum[threadIdx.x] : 0;
    sm[threadIdx.x] = v;
    __syncthreads();
    for (int off = 1; off < 512; off <<= 1) {
        int t = (threadIdx.x >= off) ? sm[threadIdx.x - off] : 0;
        __syncthreads();
        sm[threadIdx.x] += t;
        __syncthreads();
    }
    if (threadIdx.x < nb) boff[threadIdx.x] = sm[threadIdx.x] - v;
}

__global__ void scan3_kernel(int* __restrict__ rowptr, const int* __restrict__ boff,
                             int N, int E) {
    int i = blockIdx.x * blockDim.x + threadIdx.x;
    if (i < N) rowptr[i] += boff[i / SCAN_BLK];
    if (i == 0) rowptr[N] = E;
}

__global__ void scatter_kernel(const int* __restrict__ ei, const int* __restrict__ rowptr,
                               int* __restrict__ cursor, int* __restrict__ csr_eid, int E) {
    int e = blockIdx.x * blockDim.x + threadIdx.x;
    if (e >= E) return;
    int dst = ei[E + e];
    int pos = atomicAdd(&cursor[dst], 1);
    csr_eid[rowptr[dst] + pos] = e;
}

// ---------------- node projections: Q,K,V,S = X@W + b -------------------
template<int CIN, int HC>
__global__ void proj_kernel(const float* __restrict__ X,
                            const float* __restrict__ wq, const float* __restrict__ bq,
                            const float* __restrict__ wk, const float* __restrict__ bk,
                            const float* __restrict__ wv, const float* __restrict__ bv,
                            const float* __restrict__ wsk, const float* __restrict__ bsk,
                            float* __restrict__ Q, float* __restrict__ K,
                            float* __restrict__ V, float* __restrict__ S, int N)
{
    int idx = blockIdx.x * blockDim.x + threadIdx.x;
    if (idx >= N * HC) return;
    int n = idx / HC;
    int c = idx - n * HC;
    float q = bq[c], k = bk[c], v = bv[c], s = bsk[c];
    const float* xr = X + (size_t)n * CIN;
#pragma unroll
    for (int i = 0; i < CIN; ++i) {
        float xi = xr[i];
        q = fmaf(xi, wq[i * HC + c], q);
        k = fmaf(xi, wk[i * HC + c], k);
        v = fmaf(xi, wv[i * HC + c], v);
        s = fmaf(xi, wsk[i * HC + c], s);
    }
    Q[idx] = q; K[idx] = k; V[idx] = v; S[idx] = s;
}

// ---------------- edge gather, H=8: one thread per (node, head) ----------
template<int C>
__global__ void gather8_kernel(const int* __restrict__ ei,
                               const int* __restrict__ rowptr,
                               const int* __restrict__ csr_eid,
                               const float* __restrict__ ea,
                               const float* __restrict__ we,
                               const float* __restrict__ Q,
                               const float* __restrict__ K,
                               const float* __restrict__ V,
                               float* __restrict__ OUT,
                               int N, int E, float scale)
{
    const int HC = 8 * C;
    int tid = blockIdx.x * blockDim.x + threadIdx.x;
    if (tid >= N * 8) return;
    int n = tid >> 3;
    int h = tid & 7;

    float wcol[8][C];
#pragma unroll
    for (int d = 0; d < 8; ++d)
#pragma unroll
        for (int i = 0; i < C; ++i) wcol[d][i] = we[d * HC + h * C + i];

    float q[C], num[C];
#pragma unroll
    for (int i = 0; i < C; ++i) { q[i] = Q[(size_t)n * HC + h * C + i]; num[i] = 0.f; }
    float den = 0.f;

    int rs = rowptr[n], re = rowptr[n + 1];
    for (int j = rs; j < re; ++j) {
        int eid = csr_eid[j];
        int src = ei[eid];
        const float4* eap = (const float4*)(ea + (size_t)eid * 8);
        float4 a0 = eap[0], a1 = eap[1];
        const float* Kp = K + (size_t)src * HC + h * C;
        const float* Vp = V + (size_t)src * HC + h * C;
        float ec[C];
        float dot = 0.f;
#pragma unroll
        for (int i = 0; i < C; ++i) {
            float e_ = a0.x * wcol[0][i];
            e_ = fmaf(a0.y, wcol[1][i], e_);
            e_ = fmaf(a0.z, wcol[2][i], e_);
            e_ = fmaf(a0.w, wcol[3][i], e_);
            e_ = fmaf(a1.x, wcol[4][i], e_);
            e_ = fmaf(a1.y, wcol[5][i], e_);
            e_ = fmaf(a1.z, wcol[6][i], e_);
            e_ = fmaf(a1.w, wcol[7][i], e_);
            ec[i] = e_;
            dot = fmaf(q[i], Kp[i] + e_, dot);
        }
        float ex = expf(dot * scale);
        den += ex;
#pragma unroll
        for (int i = 0; i < C; ++i) num[i] = fmaf(ex, Vp[i] + ec[i], num[i]);
    }
    float inv = 1.f / (den + 1e-16f);
#pragma unroll
    for (int i = 0; i < C; ++i) OUT[(size_t)n * HC + h * C + i] = num[i] * inv;
}

// ---------------- edge gather, H=1,C=64: one wave per node ---------------
__global__ void gather64_kernel(const int* __restrict__ ei,
                                const int* __restrict__ rowptr,
                                const int* __restrict__ csr_eid,
                                const float* __restrict__ ea,
                                const float* __restrict__ we,
                                const float* __restrict__ Q,
                                const float* __restrict__ K,
                                const float* __restrict__ V,
                                float* __restrict__ OUT,
                                int N, int E, float scale)
{
    int wid = (blockIdx.x * blockDim.x + threadIdx.x) >> 6;
    int lane = threadIdx.x & 63;
    if (wid >= N) return;

    float w8[8];
#pragma unroll
    for (int d = 0; d < 8; ++d) w8[d] = we[d * 64 + lane];
    float qc = Q[(size_t)wid * 64 + lane];
    float num = 0.f, den = 0.f;

    int rs = rowptr[wid], re = rowptr[wid + 1];
    for (int j = rs; j < re; ++j) {
        int eid = csr_eid[j];
        int src = ei[eid];
        const float4* eap = (const float4*)(ea + (size_t)eid * 8);
        float4 a0 = eap[0], a1 = eap[1];
        float e_ = a0.x * w8[0];
        e_ = fmaf(a0.y, w8[1], e_);
        e_ = fmaf(a0.z, w8[2], e_);
        e_ = fmaf(a0.w, w8[3], e_);
        e_ = fmaf(a1.x, w8[4], e_);
        e_ = fmaf(a1.y, w8[5], e_);
        e_ = fmaf(a1.z, w8[6], e_);
        e_ = fmaf(a1.w, w8[7], e_);
        float kc = K[(size_t)src * 64 + lane] + e_;
        float t = qc * kc;
#pragma unroll
        for (int off = 32; off > 0; off >>= 1) t += __shfl_xor(t, off, 64);
        float ex = expf(t * scale);
        den += ex;
        num = fmaf(ex, V[(size_t)src * 64 + lane] + e_, num);
    }
    OUT[(size_t)wid * 64 + lane] = num / (den + 1e-16f);
}

// ---------------- finalize: one wave per node ----------------
// ATT = normalized attention out; g = sigmoid([att,s,att-s]@wb); h=relu(g*s+(1-g)*att)
template<int HC, bool FINAL>
__global__ void finalize_kernel(const float* __restrict__ ATT, const float* __restrict__ S,
                                const float* __restrict__ wb,
                                const float* __restrict__ wc, const float* __restrict__ bc,
                                float* __restrict__ OUT, int N)
{
    int wid = (blockIdx.x * blockDim.x + threadIdx.x) >> 6;
    int lane = threadIdx.x & 63;
    if (wid >= N) return;

    float outc = 0.f, sc = 0.f, gd = 0.f;
    if (lane < HC) {
        outc = ATT[(size_t)wid * HC + lane];
        sc = S[(size_t)wid * HC + lane];
        gd = outc * wb[lane] + sc * wb[HC + lane] + (outc - sc) * wb[2 * HC + lane];
    }
#pragma unroll
    for (int off = 32; off > 0; off >>= 1) gd += __shfl_xor(gd, off, 64);
    float g = 1.f / (1.f + expf(-gd));
    float h = g * sc + (1.f - g) * outc;
    h = fmaxf(h, 0.f);
    if (FINAL) {
        float t = (lane < HC) ? h * wc[lane] : 0.f;
#pragma unroll
        for (int off = 32; off > 0; off >>= 1) t += __shfl_xor(t, off, 64);
        if (lane == 0) OUT[wid] = t + bc[0];
    } else {
        if (lane < HC) OUT[(size_t)wid * HC + lane] = h;
    }
}

extern "C" void kernel_launch(void* const* d_in, const int* in_sizes, int n_in,
                              void* d_out, int out_size, void* d_ws, size_t ws_size,
                              hipStream_t stream) {
    const float* x  = (const float*)d_in[0];
    const int*   ei = (const int*)d_in[1];
    const float* ea = (const float*)d_in[2];
    const int N = in_sizes[0] / 32;
    const int E = in_sizes[1] / 2;

    int p = 3;
    const float *wq1=(const float*)d_in[p+0], *bq1=(const float*)d_in[p+1],
                *wk1=(const float*)d_in[p+2], *bk1=(const float*)d_in[p+3],
                *wv1=(const float*)d_in[p+4], *bv1=(const float*)d_in[p+5],
                *we1=(const float*)d_in[p+6],
                *wsk1=(const float*)d_in[p+7], *bsk1=(const float*)d_in[p+8],
                *wb1=(const float*)d_in[p+9];
    p += 10;
    const float *wq2=(const float*)d_in[p+0], *bq2=(const float*)d_in[p+1],
                *wk2=(const float*)d_in[p+2], *bk2=(const float*)d_in[p+3],
                *wv2=(const float*)d_in[p+4], *bv2=(const float*)d_in[p+5],
                *we2=(const float*)d_in[p+6],
                *wsk2=(const float*)d_in[p+7], *bsk2=(const float*)d_in[p+8],
                *wb2=(const float*)d_in[p+9];
    p += 10;
    const float *wq3=(const float*)d_in[p+0], *bq3=(const float*)d_in[p+1],
                *wk3=(const float*)d_in[p+2], *bk3=(const float*)d_in[p+3],
                *wv3=(const float*)d_in[p+4], *bv3=(const float*)d_in[p+5],
                *we3=(const float*)d_in[p+6],
                *wsk3=(const float*)d_in[p+7], *bsk3=(const float*)d_in[p+8],
                *wb3=(const float*)d_in[p+9];
    p += 10;
    const float *wc = (const float*)d_in[p+0], *bc = (const float*)d_in[p+1];

    float* out = (float*)d_out;

    // workspace layout
    size_t NB = (size_t)N * 64;
    float* ws = (float*)d_ws;
    float* Hb = ws;              // node hidden / attention out (packed per-layer HC)
    float* Qb = Hb + NB;
    float* Kb = Qb + NB;
    float* Vb = Kb + NB;
    float* Sb = Vb + NB;
    int* ip      = (int*)(Sb + NB);
    int* rowptr  = ip;                 // N+1
    int* deg     = rowptr + (N + 2);   // N (also scatter cursor)
    int* bsum    = deg + N;            // 512
    int* boff    = bsum + 512;         // 512
    int* csr_eid = boff + 512;         // E

    const int BLK = 256;
    const int NBLK = (N + SCAN_BLK - 1) / SCAN_BLK;

    // ---------------- CSR build ----------------
    hipMemsetAsync(deg, 0, (size_t)N * sizeof(int), stream);
    count_kernel<<<(E + BLK - 1) / BLK, BLK, 0, stream>>>(ei, deg, E);
    scan1_kernel<<<NBLK, SCAN_BLK, 0, stream>>>(deg, rowptr, bsum, N);
    scan2_kernel<<<1, 512, 0, stream>>>(bsum, boff, NBLK);
    scan3_kernel<<<(N + BLK - 1) / BLK, BLK, 0, stream>>>(rowptr, boff, N, E);
    hipMemsetAsync(deg, 0, (size_t)N * sizeof(int), stream);
    scatter_kernel<<<(E + BLK - 1) / BLK, BLK, 0, stream>>>(ei, rowptr, deg, csr_eid, E);

    // ---------------- layer 1: cin=32, H=8, C=6 (HC=48) ----------------
    proj_kernel<32,48><<<(N*48 + BLK-1)/BLK, BLK, 0, stream>>>(
        x, wq1,bq1, wk1,bk1, wv1,bv1, wsk1,bsk1, Qb,Kb,Vb,Sb, N);
    gather8_kernel<6><<<(N*8 + BLK-1)/BLK, BLK, 0, stream>>>(
        ei, rowptr, csr_eid, ea, we1, Qb, Kb, Vb, Hb, N, E, 1.0f/sqrtf(6.0f));
    finalize_kernel<48,false><<<(N + 3)/4, BLK, 0, stream>>>(
        Hb, Sb, wb1, nullptr, nullptr, Hb, N);

    // ---------------- layer 2: cin=48, H=8, C=3 (HC=24) ----------------
    proj_kernel<48,24><<<(N*24 + BLK-1)/BLK, BLK, 0, stream>>>(
        Hb, wq2,bq2, wk2,bk2, wv2,bv2, wsk2,bsk2, Qb,Kb,Vb,Sb, N);
    gather8_kernel<3><<<(N*8 + BLK-1)/BLK, BLK, 0, stream>>>(
        ei, rowptr, csr_eid, ea, we2, Qb, Kb, Vb, Hb, N, E, 1.0f/sqrtf(3.0f));
    finalize_kernel<24,false><<<(N + 3)/4, BLK, 0, stream>>>(
        Hb, Sb, wb2, nullptr, nullptr, Hb, N);

    // ---------------- layer 3: cin=24, H=1, C=64 (HC=64) ----------------
    proj_kernel<24,64><<<(N*64 + BLK-1)/BLK, BLK, 0, stream>>>(
        Hb, wq3,bq3, wk3,bk3, wv3,bv3, wsk3,bsk3, Qb,Kb,Vb,Sb, N);
    gather64_kernel<<<((size_t)N*64 + BLK-1)/BLK, BLK, 0, stream>>>(
        ei, rowptr, csr_eid, ea, we3, Qb, Kb, Vb, Hb, N, E, 1.0f/8.0f);
    finalize_kernel<64,true><<<(N + 3)/4, BLK, 0, stream>>>(
        Hb, Sb, wb3, wc, bc, out, N);
}

// Round 3
// 1484.556 us; speedup vs baseline: 10.3784x; 1.2672x over previous
//
#include <hip/hip_runtime.h>
#include <math.h>

#define SCAN_BLK 256

// ---------------- CSR build ----------------
__global__ void count_kernel(const int* __restrict__ ei, int* __restrict__ deg, int E) {
    int e = blockIdx.x * blockDim.x + threadIdx.x;
    if (e < E) atomicAdd(&deg[ei[E + e]], 1);
}

__global__ void scan1_kernel(const int* __restrict__ deg, int* __restrict__ part,
                             int* __restrict__ bsum, int N) {
    __shared__ int sm[SCAN_BLK];
    int i = blockIdx.x * SCAN_BLK + threadIdx.x;
    int v = (i < N) ? deg[i] : 0;
    sm[threadIdx.x] = v;
    __syncthreads();
    for (int off = 1; off < SCAN_BLK; off <<= 1) {
        int t = (threadIdx.x >= off) ? sm[threadIdx.x - off] : 0;
        __syncthreads();
        sm[threadIdx.x] += t;
        __syncthreads();
    }
    if (i < N) part[i] = sm[threadIdx.x] - v;
    if (threadIdx.x == SCAN_BLK - 1) bsum[blockIdx.x] = sm[threadIdx.x];
}

__global__ void scan2_kernel(const int* __restrict__ bsum, int* __restrict__ boff, int nb) {
    __shared__ int sm[512];
    int v = (threadIdx.x < nb) ? bsum[threadIdx.x] : 0;
    sm[threadIdx.x] = v;
    __syncthreads();
    for (int off = 1; off < 512; off <<= 1) {
        int t = (threadIdx.x >= off) ? sm[threadIdx.x - off] : 0;
        __syncthreads();
        sm[threadIdx.x] += t;
        __syncthreads();
    }
    if (threadIdx.x < nb) boff[threadIdx.x] = sm[threadIdx.x] - v;
}

__global__ void scan3_kernel(int* __restrict__ rowptr, const int* __restrict__ boff,
                             int N, int E) {
    int i = blockIdx.x * blockDim.x + threadIdx.x;
    if (i < N) rowptr[i] += boff[i / SCAN_BLK];
    if (i == 0) rowptr[N] = E;
}

// scatter: also writes src_perm so gathers avoid the ei[eid] indirection
__global__ void scatter_kernel(const int* __restrict__ ei, const int* __restrict__ rowptr,
                               int* __restrict__ cursor, int* __restrict__ csr_eid,
                               int* __restrict__ srcp, int E) {
    int e = blockIdx.x * blockDim.x + threadIdx.x;
    if (e >= E) return;
    int dst = ei[E + e];
    int pos = atomicAdd(&cursor[dst], 1);
    int idx = rowptr[dst] + pos;
    csr_eid[idx] = e;
    srcp[idx] = ei[e];
}

// ---------------- node projections: Q,K,V,S = X@W + b -------------------
template<int CIN, int HC>
__global__ void proj_kernel(const float* __restrict__ X,
                            const float* __restrict__ wq, const float* __restrict__ bq,
                            const float* __restrict__ wk, const float* __restrict__ bk,
                            const float* __restrict__ wv, const float* __restrict__ bv,
                            const float* __restrict__ wsk, const float* __restrict__ bsk,
                            float* __restrict__ Q, float* __restrict__ K,
                            float* __restrict__ V, float* __restrict__ S, int N)
{
    int idx = blockIdx.x * blockDim.x + threadIdx.x;
    if (idx >= N * HC) return;
    int n = idx / HC;
    int c = idx - n * HC;
    float q = bq[c], k = bk[c], v = bv[c], s = bsk[c];
    const float* xr = X + (size_t)n * CIN;
#pragma unroll
    for (int i = 0; i < CIN; ++i) {
        float xi = xr[i];
        q = fmaf(xi, wq[i * HC + c], q);
        k = fmaf(xi, wk[i * HC + c], k);
        v = fmaf(xi, wv[i * HC + c], v);
        s = fmaf(xi, wsk[i * HC + c], s);
    }
    Q[idx] = q; K[idx] = k; V[idx] = v; S[idx] = s;
}

// ---- fused gather+gate, H=8: thread per (node, head), factorized e -----
// dot = q.K[src] + (we^T q).ea ; num = sum ex*V + we.(sum ex*ea)
template<int C>
__global__ void gather8f_kernel(const int* __restrict__ rowptr,
                                const int* __restrict__ csr_eid,
                                const int* __restrict__ srcp,
                                const float* __restrict__ ea,
                                const float* __restrict__ we,
                                const float* __restrict__ Q,
                                const float* __restrict__ K,
                                const float* __restrict__ V,
                                const float* __restrict__ S,
                                const float* __restrict__ wb,
                                float* __restrict__ OUT,
                                int N, float scale)
{
    const int HC = 8 * C;
    int tid = blockIdx.x * blockDim.x + threadIdx.x;
    int n = tid >> 3;
    int h = tid & 7;
    if (n >= N) return;

    float q[C];
    const float* Qp = Q + (size_t)n * HC + h * C;
#pragma unroll
    for (int c = 0; c < C; ++c) q[c] = Qp[c];

    // qe[d] = sum_c we[d][h*C+c] * q[c]
    float qe[8];
#pragma unroll
    for (int d = 0; d < 8; ++d) {
        float t = 0.f;
#pragma unroll
        for (int c = 0; c < C; ++c) t = fmaf(we[d * HC + h * C + c], q[c], t);
        qe[d] = t;
    }

    float num[C];
#pragma unroll
    for (int c = 0; c < C; ++c) num[c] = 0.f;
    float sacc[8];
#pragma unroll
    for (int d = 0; d < 8; ++d) sacc[d] = 0.f;
    float den = 0.f;

    int rs = rowptr[n], re = rowptr[n + 1];
    for (int j = rs; j < re; ++j) {
        int src = srcp[j];
        int eid = csr_eid[j];
        const float4* eap = (const float4*)(ea + (size_t)eid * 8);
        float4 a0 = eap[0], a1 = eap[1];
        const float* Kp = K + (size_t)src * HC + h * C;
        const float* Vp = V + (size_t)src * HC + h * C;
        float dot = 0.f;
#pragma unroll
        for (int c = 0; c < C; ++c) dot = fmaf(q[c], Kp[c], dot);
        float qea = qe[0] * a0.x;
        qea = fmaf(qe[1], a0.y, qea);
        qea = fmaf(qe[2], a0.z, qea);
        qea = fmaf(qe[3], a0.w, qea);
        qea = fmaf(qe[4], a1.x, qea);
        qea = fmaf(qe[5], a1.y, qea);
        qea = fmaf(qe[6], a1.z, qea);
        qea = fmaf(qe[7], a1.w, qea);
        float ex = expf((dot + qea) * scale);
        den += ex;
#pragma unroll
        for (int c = 0; c < C; ++c) num[c] = fmaf(ex, Vp[c], num[c]);
        sacc[0] = fmaf(ex, a0.x, sacc[0]);
        sacc[1] = fmaf(ex, a0.y, sacc[1]);
        sacc[2] = fmaf(ex, a0.z, sacc[2]);
        sacc[3] = fmaf(ex, a0.w, sacc[3]);
        sacc[4] = fmaf(ex, a1.x, sacc[4]);
        sacc[5] = fmaf(ex, a1.y, sacc[5]);
        sacc[6] = fmaf(ex, a1.z, sacc[6]);
        sacc[7] = fmaf(ex, a1.w, sacc[7]);
    }

    float inv = 1.f / (den + 1e-16f);
    float outc[C], sc[C];
    float gd = 0.f;
#pragma unroll
    for (int c = 0; c < C; ++c) {
        float e_ = 0.f;
#pragma unroll
        for (int d = 0; d < 8; ++d) e_ = fmaf(we[d * HC + h * C + c], sacc[d], e_);
        float o = (num[c] + e_) * inv;
        float s_ = S[(size_t)n * HC + h * C + c];
        outc[c] = o;
        sc[c] = s_;
        gd += o * wb[h * C + c] + s_ * wb[HC + h * C + c] + (o - s_) * wb[2 * HC + h * C + c];
    }
    // 8-lane group reduce (heads of one node are lane-contiguous, 8-aligned)
    gd += __shfl_xor(gd, 1, 64);
    gd += __shfl_xor(gd, 2, 64);
    gd += __shfl_xor(gd, 4, 64);
    float g = 1.f / (1.f + expf(-gd));
#pragma unroll
    for (int c = 0; c < C; ++c) {
        float hh = fmaxf(g * sc[c] + (1.f - g) * outc[c], 0.f);
        OUT[(size_t)n * HC + h * C + c] = hh;
    }
}

// ---- fused gather+gate+classifier, H=1,C=64: wave per node, 2-edge unroll ----
__global__ void gather64f_kernel(const int* __restrict__ rowptr,
                                 const int* __restrict__ csr_eid,
                                 const int* __restrict__ srcp,
                                 const float* __restrict__ ea,
                                 const float* __restrict__ we,
                                 const float* __restrict__ Q,
                                 const float* __restrict__ K,
                                 const float* __restrict__ V,
                                 const float* __restrict__ S,
                                 const float* __restrict__ wb,
                                 const float* __restrict__ wc,
                                 const float* __restrict__ bc,
                                 float* __restrict__ OUT,
                                 int N, float scale)
{
    int wid = (blockIdx.x * blockDim.x + threadIdx.x) >> 6;
    int lane = threadIdx.x & 63;
    if (wid >= N) return;

    float w8[8];
#pragma unroll
    for (int d = 0; d < 8; ++d) w8[d] = we[d * 64 + lane];
    float qc = Q[(size_t)wid * 64 + lane];
    float num = 0.f, den = 0.f;

    int rs = rowptr[wid], re = rowptr[wid + 1];
    int j = rs;
    for (; j + 1 < re; j += 2) {
        int s0 = srcp[j], s1 = srcp[j + 1];
        int e0 = csr_eid[j], e1 = csr_eid[j + 1];
        const float4* ep0 = (const float4*)(ea + (size_t)e0 * 8);
        const float4* ep1 = (const float4*)(ea + (size_t)e1 * 8);
        float4 a00 = ep0[0], a01 = ep0[1];
        float4 a10 = ep1[0], a11 = ep1[1];
        float kv0 = K[(size_t)s0 * 64 + lane];
        float kv1 = K[(size_t)s1 * 64 + lane];
        float vv0 = V[(size_t)s0 * 64 + lane];
        float vv1 = V[(size_t)s1 * 64 + lane];
        float ee0 = a00.x * w8[0];
        ee0 = fmaf(a00.y, w8[1], ee0); ee0 = fmaf(a00.z, w8[2], ee0);
        ee0 = fmaf(a00.w, w8[3], ee0); ee0 = fmaf(a01.x, w8[4], ee0);
        ee0 = fmaf(a01.y, w8[5], ee0); ee0 = fmaf(a01.z, w8[6], ee0);
        ee0 = fmaf(a01.w, w8[7], ee0);
        float ee1 = a10.x * w8[0];
        ee1 = fmaf(a10.y, w8[1], ee1); ee1 = fmaf(a10.z, w8[2], ee1);
        ee1 = fmaf(a10.w, w8[3], ee1); ee1 = fmaf(a11.x, w8[4], ee1);
        ee1 = fmaf(a11.y, w8[5], ee1); ee1 = fmaf(a11.z, w8[6], ee1);
        ee1 = fmaf(a11.w, w8[7], ee1);
        float t0 = qc * (kv0 + ee0);
        float t1 = qc * (kv1 + ee1);
#pragma unroll
        for (int off = 32; off > 0; off >>= 1) {
            t0 += __shfl_xor(t0, off, 64);
            t1 += __shfl_xor(t1, off, 64);
        }
        float ex0 = expf(t0 * scale);
        float ex1 = expf(t1 * scale);
        den += ex0 + ex1;
        num = fmaf(ex0, vv0 + ee0, num);
        num = fmaf(ex1, vv1 + ee1, num);
    }
    if (j < re) {
        int s0 = srcp[j];
        int e0 = csr_eid[j];
        const float4* ep0 = (const float4*)(ea + (size_t)e0 * 8);
        float4 a00 = ep0[0], a01 = ep0[1];
        float ee0 = a00.x * w8[0];
        ee0 = fmaf(a00.y, w8[1], ee0); ee0 = fmaf(a00.z, w8[2], ee0);
        ee0 = fmaf(a00.w, w8[3], ee0); ee0 = fmaf(a01.x, w8[4], ee0);
        ee0 = fmaf(a01.y, w8[5], ee0); ee0 = fmaf(a01.z, w8[6], ee0);
        ee0 = fmaf(a01.w, w8[7], ee0);
        float t0 = qc * (K[(size_t)s0 * 64 + lane] + ee0);
#pragma unroll
        for (int off = 32; off > 0; off >>= 1) t0 += __shfl_xor(t0, off, 64);
        float ex0 = expf(t0 * scale);
        den += ex0;
        num = fmaf(ex0, V[(size_t)s0 * 64 + lane] + ee0, num);
    }

    float o = num / (den + 1e-16f);
    float s_ = S[(size_t)wid * 64 + lane];
    float gd = o * wb[lane] + s_ * wb[64 + lane] + (o - s_) * wb[128 + lane];
#pragma unroll
    for (int off = 32; off > 0; off >>= 1) gd += __shfl_xor(gd, off, 64);
    float g = 1.f / (1.f + expf(-gd));
    float hh = fmaxf(g * s_ + (1.f - g) * o, 0.f);
    float t = hh * wc[lane];
#pragma unroll
    for (int off = 32; off > 0; off >>= 1) t += __shfl_xor(t, off, 64);
    if (lane == 0) OUT[wid] = t + bc[0];
}

extern "C" void kernel_launch(void* const* d_in, const int* in_sizes, int n_in,
                              void* d_out, int out_size, void* d_ws, size_t ws_size,
                              hipStream_t stream) {
    const float* x  = (const float*)d_in[0];
    const int*   ei = (const int*)d_in[1];
    const float* ea = (const float*)d_in[2];
    const int N = in_sizes[0] / 32;
    const int E = in_sizes[1] / 2;

    int p = 3;
    const float *wq1=(const float*)d_in[p+0], *bq1=(const float*)d_in[p+1],
                *wk1=(const float*)d_in[p+2], *bk1=(const float*)d_in[p+3],
                *wv1=(const float*)d_in[p+4], *bv1=(const float*)d_in[p+5],
                *we1=(const float*)d_in[p+6],
                *wsk1=(const float*)d_in[p+7], *bsk1=(const float*)d_in[p+8],
                *wb1=(const float*)d_in[p+9];
    p += 10;
    const float *wq2=(const float*)d_in[p+0], *bq2=(const float*)d_in[p+1],
                *wk2=(const float*)d_in[p+2], *bk2=(const float*)d_in[p+3],
                *wv2=(const float*)d_in[p+4], *bv2=(const float*)d_in[p+5],
                *we2=(const float*)d_in[p+6],
                *wsk2=(const float*)d_in[p+7], *bsk2=(const float*)d_in[p+8],
                *wb2=(const float*)d_in[p+9];
    p += 10;
    const float *wq3=(const float*)d_in[p+0], *bq3=(const float*)d_in[p+1],
                *wk3=(const float*)d_in[p+2], *bk3=(const float*)d_in[p+3],
                *wv3=(const float*)d_in[p+4], *bv3=(const float*)d_in[p+5],
                *we3=(const float*)d_in[p+6],
                *wsk3=(const float*)d_in[p+7], *bsk3=(const float*)d_in[p+8],
                *wb3=(const float*)d_in[p+9];
    p += 10;
    const float *wc = (const float*)d_in[p+0], *bc = (const float*)d_in[p+1];

    float* out = (float*)d_out;

    // workspace layout
    size_t NB = (size_t)N * 64;
    float* ws = (float*)d_ws;
    float* Hb = ws;
    float* Qb = Hb + NB;
    float* Kb = Qb + NB;
    float* Vb = Kb + NB;
    float* Sb = Vb + NB;
    int* ip      = (int*)(Sb + NB);
    int* rowptr  = ip;                 // N+1
    int* deg     = rowptr + (N + 2);   // N (also scatter cursor)
    int* bsum    = deg + N;            // 512
    int* boff    = bsum + 512;         // 512
    int* csr_eid = boff + 512;         // E
    int* srcp    = csr_eid + E;        // E

    const int BLK = 256;
    const int NBLK = (N + SCAN_BLK - 1) / SCAN_BLK;

    // ---------------- CSR build ----------------
    hipMemsetAsync(deg, 0, (size_t)N * sizeof(int), stream);
    count_kernel<<<(E + BLK - 1) / BLK, BLK, 0, stream>>>(ei, deg, E);
    scan1_kernel<<<NBLK, SCAN_BLK, 0, stream>>>(deg, rowptr, bsum, N);
    scan2_kernel<<<1, 512, 0, stream>>>(bsum, boff, NBLK);
    scan3_kernel<<<(N + BLK - 1) / BLK, BLK, 0, stream>>>(rowptr, boff, N, E);
    hipMemsetAsync(deg, 0, (size_t)N * sizeof(int), stream);
    scatter_kernel<<<(E + BLK - 1) / BLK, BLK, 0, stream>>>(ei, rowptr, deg, csr_eid, srcp, E);

    // ---------------- layer 1: cin=32, H=8, C=6 (HC=48) ----------------
    proj_kernel<32,48><<<(N*48 + BLK-1)/BLK, BLK, 0, stream>>>(
        x, wq1,bq1, wk1,bk1, wv1,bv1, wsk1,bsk1, Qb,Kb,Vb,Sb, N);
    gather8f_kernel<6><<<(N*8 + BLK-1)/BLK, BLK, 0, stream>>>(
        rowptr, csr_eid, srcp, ea, we1, Qb, Kb, Vb, Sb, wb1, Hb, N, 1.0f/sqrtf(6.0f));

    // ---------------- layer 2: cin=48, H=8, C=3 (HC=24) ----------------
    proj_kernel<48,24><<<(N*24 + BLK-1)/BLK, BLK, 0, stream>>>(
        Hb, wq2,bq2, wk2,bk2, wv2,bv2, wsk2,bsk2, Qb,Kb,Vb,Sb, N);
    gather8f_kernel<3><<<(N*8 + BLK-1)/BLK, BLK, 0, stream>>>(
        rowptr, csr_eid, srcp, ea, we2, Qb, Kb, Vb, Sb, wb2, Hb, N, 1.0f/sqrtf(3.0f));

    // ---------------- layer 3: cin=24, H=1, C=64 (HC=64) ----------------
    proj_kernel<24,64><<<(N*64 + BLK-1)/BLK, BLK, 0, stream>>>(
        Hb, wq3,bq3, wk3,bk3, wv3,bv3, wsk3,bsk3, Qb,Kb,Vb,Sb, N);
    gather64f_kernel<<<((size_t)N*64 + BLK-1)/BLK, BLK, 0, stream>>>(
        rowptr, csr_eid, srcp, ea, we3, Qb, Kb, Vb, Sb, wb3, wc, bc, out, N, 1.0f/8.0f);
}

// Round 4
// 1369.958 us; speedup vs baseline: 11.2466x; 1.0837x over previous
//
#include <hip/hip_runtime.h>
#include <math.h>

#define SCAN_BLK 256

// ---------------- CSR build ----------------
__global__ void count_kernel(const int* __restrict__ ei, int* __restrict__ deg, int E) {
    int e = blockIdx.x * blockDim.x + threadIdx.x;
    if (e < E) atomicAdd(&deg[ei[E + e]], 1);
}

__global__ void scan1_kernel(const int* __restrict__ deg, int* __restrict__ part,
                             int* __restrict__ bsum, int N) {
    __shared__ int sm[SCAN_BLK];
    int i = blockIdx.x * SCAN_BLK + threadIdx.x;
    int v = (i < N) ? deg[i] : 0;
    sm[threadIdx.x] = v;
    __syncthreads();
    for (int off = 1; off < SCAN_BLK; off <<= 1) {
        int t = (threadIdx.x >= off) ? sm[threadIdx.x - off] : 0;
        __syncthreads();
        sm[threadIdx.x] += t;
        __syncthreads();
    }
    if (i < N) part[i] = sm[threadIdx.x] - v;
    if (threadIdx.x == SCAN_BLK - 1) bsum[blockIdx.x] = sm[threadIdx.x];
}

__global__ void scan2_kernel(const int* __restrict__ bsum, int* __restrict__ boff, int nb) {
    __shared__ int sm[512];
    int v = (threadIdx.x < nb) ? bsum[threadIdx.x] : 0;
    sm[threadIdx.x] = v;
    __syncthreads();
    for (int off = 1; off < 512; off <<= 1) {
        int t = (threadIdx.x >= off) ? sm[threadIdx.x - off] : 0;
        __syncthreads();
        sm[threadIdx.x] += t;
        __syncthreads();
    }
    if (threadIdx.x < nb) boff[threadIdx.x] = sm[threadIdx.x] - v;
}

__global__ void scan3_kernel(int* __restrict__ rowptr, const int* __restrict__ boff,
                             int N, int E) {
    int i = blockIdx.x * blockDim.x + threadIdx.x;
    if (i < N) rowptr[i] += boff[i / SCAN_BLK];
    if (i == 0) rowptr[N] = E;
}

// scatter: rec[j] = (src, eid) packed
__global__ void scatter_kernel(const int* __restrict__ ei, const int* __restrict__ rowptr,
                               int* __restrict__ cursor, int2* __restrict__ rec, int E) {
    int e = blockIdx.x * blockDim.x + threadIdx.x;
    if (e >= E) return;
    int dst = ei[E + e];
    int pos = atomicAdd(&cursor[dst], 1);
    rec[rowptr[dst] + pos] = make_int2(ei[e], e);
}

// ------- node projections: Q,K,V (head-padded layout), S (unpadded) -------
template<int CIN, int H, int C, int CP>
__global__ void proj_kernel(const float* __restrict__ X,
                            const float* __restrict__ wq, const float* __restrict__ bq,
                            const float* __restrict__ wk, const float* __restrict__ bk,
                            const float* __restrict__ wv, const float* __restrict__ bv,
                            const float* __restrict__ wsk, const float* __restrict__ bsk,
                            float* __restrict__ Q, float* __restrict__ K,
                            float* __restrict__ V, float* __restrict__ S, int N)
{
    const int HC = H * C;
    int idx = blockIdx.x * blockDim.x + threadIdx.x;
    if (idx >= N * HC) return;
    int n = idx / HC;
    int c = idx - n * HC;
    int h = c / C;
    int cc = c - h * C;
    float q = bq[c], k = bk[c], v = bv[c], s = bsk[c];
    const float* xr = X + (size_t)n * CIN;
#pragma unroll
    for (int i = 0; i < CIN; ++i) {
        float xi = xr[i];
        q = fmaf(xi, wq[i * HC + c], q);
        k = fmaf(xi, wk[i * HC + c], k);
        v = fmaf(xi, wv[i * HC + c], v);
        s = fmaf(xi, wsk[i * HC + c], s);
    }
    size_t po = (size_t)n * (H * CP) + h * CP + cc;
    Q[po] = q; K[po] = k; V[po] = v;
    S[(size_t)n * HC + c] = s;
}

// ---- fused gather+gate, H=8: thread per (node, head), factorized e -----
template<int C, int CP>
__global__ void gather8f_kernel(const int* __restrict__ rowptr,
                                const int2* __restrict__ rec,
                                const float* __restrict__ ea,
                                const float* __restrict__ we,
                                const float* __restrict__ Q,
                                const float* __restrict__ K,
                                const float* __restrict__ V,
                                const float* __restrict__ S,
                                const float* __restrict__ wb,
                                float* __restrict__ OUT,
                                int N, float scale)
{
    const int HC = 8 * C;
    const int HCP = 8 * CP;
    int tid = blockIdx.x * blockDim.x + threadIdx.x;
    int n = tid >> 3;
    int h = tid & 7;
    if (n >= N) return;

    float q[C];
    const float* Qp = Q + (size_t)n * HCP + h * CP;
#pragma unroll
    for (int c = 0; c < C; ++c) q[c] = Qp[c];

    float qe[8];
#pragma unroll
    for (int d = 0; d < 8; ++d) {
        float t = 0.f;
#pragma unroll
        for (int c = 0; c < C; ++c) t = fmaf(we[d * HC + h * C + c], q[c], t);
        qe[d] = t;
    }

    float num[C];
#pragma unroll
    for (int c = 0; c < C; ++c) num[c] = 0.f;
    float sacc[8];
#pragma unroll
    for (int d = 0; d < 8; ++d) sacc[d] = 0.f;
    float den = 0.f;

    int rs = rowptr[n], re = rowptr[n + 1];
    int j = rs;
    for (; j + 1 < re; j += 2) {
        int2 r0 = rec[j], r1 = rec[j + 1];
        float4 a00 = *(const float4*)(ea + (size_t)r0.y * 8);
        float4 a01 = *(const float4*)(ea + (size_t)r0.y * 8 + 4);
        float4 a10 = *(const float4*)(ea + (size_t)r1.y * 8);
        float4 a11 = *(const float4*)(ea + (size_t)r1.y * 8 + 4);
        const float* K0 = K + (size_t)r0.x * HCP + h * CP;
        const float* V0 = V + (size_t)r0.x * HCP + h * CP;
        const float* K1 = K + (size_t)r1.x * HCP + h * CP;
        const float* V1 = V + (size_t)r1.x * HCP + h * CP;
        float k0[CP], v0[CP], k1[CP], v1[CP];
#pragma unroll
        for (int t4 = 0; t4 < CP / 4; ++t4) {
            *(float4*)(k0 + 4 * t4) = *(const float4*)(K0 + 4 * t4);
            *(float4*)(v0 + 4 * t4) = *(const float4*)(V0 + 4 * t4);
            *(float4*)(k1 + 4 * t4) = *(const float4*)(K1 + 4 * t4);
            *(float4*)(v1 + 4 * t4) = *(const float4*)(V1 + 4 * t4);
        }
        float d0 = 0.f, d1 = 0.f;
#pragma unroll
        for (int c = 0; c < C; ++c) {
            d0 = fmaf(q[c], k0[c], d0);
            d1 = fmaf(q[c], k1[c], d1);
        }
        float qa0 = qe[0] * a00.x;
        qa0 = fmaf(qe[1], a00.y, qa0); qa0 = fmaf(qe[2], a00.z, qa0);
        qa0 = fmaf(qe[3], a00.w, qa0); qa0 = fmaf(qe[4], a01.x, qa0);
        qa0 = fmaf(qe[5], a01.y, qa0); qa0 = fmaf(qe[6], a01.z, qa0);
        qa0 = fmaf(qe[7], a01.w, qa0);
        float qa1 = qe[0] * a10.x;
        qa1 = fmaf(qe[1], a10.y, qa1); qa1 = fmaf(qe[2], a10.z, qa1);
        qa1 = fmaf(qe[3], a10.w, qa1); qa1 = fmaf(qe[4], a11.x, qa1);
        qa1 = fmaf(qe[5], a11.y, qa1); qa1 = fmaf(qe[6], a11.z, qa1);
        qa1 = fmaf(qe[7], a11.w, qa1);
        float ex0 = __expf((d0 + qa0) * scale);
        float ex1 = __expf((d1 + qa1) * scale);
        den += ex0 + ex1;
#pragma unroll
        for (int c = 0; c < C; ++c) {
            num[c] = fmaf(ex0, v0[c], num[c]);
            num[c] = fmaf(ex1, v1[c], num[c]);
        }
        sacc[0] = fmaf(ex0, a00.x, fmaf(ex1, a10.x, sacc[0]));
        sacc[1] = fmaf(ex0, a00.y, fmaf(ex1, a10.y, sacc[1]));
        sacc[2] = fmaf(ex0, a00.z, fmaf(ex1, a10.z, sacc[2]));
        sacc[3] = fmaf(ex0, a00.w, fmaf(ex1, a10.w, sacc[3]));
        sacc[4] = fmaf(ex0, a01.x, fmaf(ex1, a11.x, sacc[4]));
        sacc[5] = fmaf(ex0, a01.y, fmaf(ex1, a11.y, sacc[5]));
        sacc[6] = fmaf(ex0, a01.z, fmaf(ex1, a11.z, sacc[6]));
        sacc[7] = fmaf(ex0, a01.w, fmaf(ex1, a11.w, sacc[7]));
    }
    if (j < re) {
        int2 r0 = rec[j];
        float4 a00 = *(const float4*)(ea + (size_t)r0.y * 8);
        float4 a01 = *(const float4*)(ea + (size_t)r0.y * 8 + 4);
        const float* K0 = K + (size_t)r0.x * HCP + h * CP;
        const float* V0 = V + (size_t)r0.x * HCP + h * CP;
        float k0[CP], v0[CP];
#pragma unroll
        for (int t4 = 0; t4 < CP / 4; ++t4) {
            *(float4*)(k0 + 4 * t4) = *(const float4*)(K0 + 4 * t4);
            *(float4*)(v0 + 4 * t4) = *(const float4*)(V0 + 4 * t4);
        }
        float d0 = 0.f;
#pragma unroll
        for (int c = 0; c < C; ++c) d0 = fmaf(q[c], k0[c], d0);
        float qa0 = qe[0] * a00.x;
        qa0 = fmaf(qe[1], a00.y, qa0); qa0 = fmaf(qe[2], a00.z, qa0);
        qa0 = fmaf(qe[3], a00.w, qa0); qa0 = fmaf(qe[4], a01.x, qa0);
        qa0 = fmaf(qe[5], a01.y, qa0); qa0 = fmaf(qe[6], a01.z, qa0);
        qa0 = fmaf(qe[7], a01.w, qa0);
        float ex0 = __expf((d0 + qa0) * scale);
        den += ex0;
#pragma unroll
        for (int c = 0; c < C; ++c) num[c] = fmaf(ex0, v0[c], num[c]);
        sacc[0] = fmaf(ex0, a00.x, sacc[0]);
        sacc[1] = fmaf(ex0, a00.y, sacc[1]);
        sacc[2] = fmaf(ex0, a00.z, sacc[2]);
        sacc[3] = fmaf(ex0, a00.w, sacc[3]);
        sacc[4] = fmaf(ex0, a01.x, sacc[4]);
        sacc[5] = fmaf(ex0, a01.y, sacc[5]);
        sacc[6] = fmaf(ex0, a01.z, sacc[6]);
        sacc[7] = fmaf(ex0, a01.w, sacc[7]);
    }

    float inv = 1.f / (den + 1e-16f);
    float outc[C], sc[C];
    float gd = 0.f;
#pragma unroll
    for (int c = 0; c < C; ++c) {
        float e_ = 0.f;
#pragma unroll
        for (int d = 0; d < 8; ++d) e_ = fmaf(we[d * HC + h * C + c], sacc[d], e_);
        float o = (num[c] + e_) * inv;
        float s_ = S[(size_t)n * HC + h * C + c];
        outc[c] = o;
        sc[c] = s_;
        gd += o * wb[h * C + c] + s_ * wb[HC + h * C + c] + (o - s_) * wb[2 * HC + h * C + c];
    }
    gd += __shfl_xor(gd, 1, 8);
    gd += __shfl_xor(gd, 2, 8);
    gd += __shfl_xor(gd, 4, 8);
    float g = 1.f / (1.f + __expf(-gd));
#pragma unroll
    for (int c = 0; c < C; ++c) {
        float hh = fmaxf(g * sc[c] + (1.f - g) * outc[c], 0.f);
        OUT[(size_t)n * HC + h * C + c] = hh;
    }
}

// ---- fused gather+gate+classifier, H=1,C=64: 16 lanes per node ----
__global__ void gather64f_kernel(const int* __restrict__ rowptr,
                                 const int2* __restrict__ rec,
                                 const float* __restrict__ ea,
                                 const float* __restrict__ we,
                                 const float* __restrict__ Q,
                                 const float* __restrict__ K,
                                 const float* __restrict__ V,
                                 const float* __restrict__ S,
                                 const float* __restrict__ wb,
                                 const float* __restrict__ wc,
                                 const float* __restrict__ bc,
                                 float* __restrict__ OUT,
                                 int N, float scale)
{
    int grp = (blockIdx.x * blockDim.x + threadIdx.x) >> 4;   // node
    int l16 = threadIdx.x & 15;                               // 4-ch slot
    if (grp >= N) return;
    int c0 = l16 << 2;

    float wv[8][4];
#pragma unroll
    for (int d = 0; d < 8; ++d) *(float4*)wv[d] = *(const float4*)(we + d * 64 + c0);
    float4 qv = *(const float4*)(Q + (size_t)grp * 64 + c0);

    float num0 = 0.f, num1 = 0.f, num2 = 0.f, num3 = 0.f, den = 0.f;
    int rs = rowptr[grp], re = rowptr[grp + 1];
    int j = rs;
    for (; j + 1 < re; j += 2) {
        int2 r0 = rec[j], r1 = rec[j + 1];
        float4 a00 = *(const float4*)(ea + (size_t)r0.y * 8);
        float4 a01 = *(const float4*)(ea + (size_t)r0.y * 8 + 4);
        float4 a10 = *(const float4*)(ea + (size_t)r1.y * 8);
        float4 a11 = *(const float4*)(ea + (size_t)r1.y * 8 + 4);
        float4 k0 = *(const float4*)(K + (size_t)r0.x * 64 + c0);
        float4 v0 = *(const float4*)(V + (size_t)r0.x * 64 + c0);
        float4 k1 = *(const float4*)(K + (size_t)r1.x * 64 + c0);
        float4 v1 = *(const float4*)(V + (size_t)r1.x * 64 + c0);
        float e0[4], e1[4];
#pragma unroll
        for (int c = 0; c < 4; ++c) {
            float t = a00.x * wv[0][c];
            t = fmaf(a00.y, wv[1][c], t); t = fmaf(a00.z, wv[2][c], t);
            t = fmaf(a00.w, wv[3][c], t); t = fmaf(a01.x, wv[4][c], t);
            t = fmaf(a01.y, wv[5][c], t); t = fmaf(a01.z, wv[6][c], t);
            t = fmaf(a01.w, wv[7][c], t);
            e0[c] = t;
            float u = a10.x * wv[0][c];
            u = fmaf(a10.y, wv[1][c], u); u = fmaf(a10.z, wv[2][c], u);
            u = fmaf(a10.w, wv[3][c], u); u = fmaf(a11.x, wv[4][c], u);
            u = fmaf(a11.y, wv[5][c], u); u = fmaf(a11.z, wv[6][c], u);
            u = fmaf(a11.w, wv[7][c], u);
            e1[c] = u;
        }
        float t0 = qv.x * (k0.x + e0[0]);
        t0 = fmaf(qv.y, k0.y + e0[1], t0);
        t0 = fmaf(qv.z, k0.z + e0[2], t0);
        t0 = fmaf(qv.w, k0.w + e0[3], t0);
        float t1 = qv.x * (k1.x + e1[0]);
        t1 = fmaf(qv.y, k1.y + e1[1], t1);
        t1 = fmaf(qv.z, k1.z + e1[2], t1);
        t1 = fmaf(qv.w, k1.w + e1[3], t1);
#pragma unroll
        for (int off = 8; off > 0; off >>= 1) {
            t0 += __shfl_xor(t0, off, 16);
            t1 += __shfl_xor(t1, off, 16);
        }
        float ex0 = __expf(t0 * scale);
        float ex1 = __expf(t1 * scale);
        den += ex0 + ex1;
        num0 = fmaf(ex0, v0.x + e0[0], fmaf(ex1, v1.x + e1[0], num0));
        num1 = fmaf(ex0, v0.y + e0[1], fmaf(ex1, v1.y + e1[1], num1));
        num2 = fmaf(ex0, v0.z + e0[2], fmaf(ex1, v1.z + e1[2], num2));
        num3 = fmaf(ex0, v0.w + e0[3], fmaf(ex1, v1.w + e1[3], num3));
    }
    if (j < re) {
        int2 r0 = rec[j];
        float4 a00 = *(const float4*)(ea + (size_t)r0.y * 8);
        float4 a01 = *(const float4*)(ea + (size_t)r0.y * 8 + 4);
        float4 k0 = *(const float4*)(K + (size_t)r0.x * 64 + c0);
        float4 v0 = *(const float4*)(V + (size_t)r0.x * 64 + c0);
        float e0[4];
#pragma unroll
        for (int c = 0; c < 4; ++c) {
            float t = a00.x * wv[0][c];
            t = fmaf(a00.y, wv[1][c], t); t = fmaf(a00.z, wv[2][c], t);
            t = fmaf(a00.w, wv[3][c], t); t = fmaf(a01.x, wv[4][c], t);
            t = fmaf(a01.y, wv[5][c], t); t = fmaf(a01.z, wv[6][c], t);
            t = fmaf(a01.w, wv[7][c], t);
            e0[c] = t;
        }
        float t0 = qv.x * (k0.x + e0[0]);
        t0 = fmaf(qv.y, k0.y + e0[1], t0);
        t0 = fmaf(qv.z, k0.z + e0[2], t0);
        t0 = fmaf(qv.w, k0.w + e0[3], t0);
#pragma unroll
        for (int off = 8; off > 0; off >>= 1) t0 += __shfl_xor(t0, off, 16);
        float ex0 = __expf(t0 * scale);
        den += ex0;
        num0 = fmaf(ex0, v0.x + e0[0], num0);
        num1 = fmaf(ex0, v0.y + e0[1], num1);
        num2 = fmaf(ex0, v0.z + e0[2], num2);
        num3 = fmaf(ex0, v0.w + e0[3], num3);
    }

    float inv = 1.f / (den + 1e-16f);
    float o0 = num0 * inv, o1 = num1 * inv, o2 = num2 * inv, o3 = num3 * inv;
    float4 sv  = *(const float4*)(S + (size_t)grp * 64 + c0);
    float4 wb0 = *(const float4*)(wb + c0);
    float4 wb1 = *(const float4*)(wb + 64 + c0);
    float4 wb2 = *(const float4*)(wb + 128 + c0);
    float gd = o0 * wb0.x + sv.x * wb1.x + (o0 - sv.x) * wb2.x;
    gd += o1 * wb0.y + sv.y * wb1.y + (o1 - sv.y) * wb2.y;
    gd += o2 * wb0.z + sv.z * wb1.z + (o2 - sv.z) * wb2.z;
    gd += o3 * wb0.w + sv.w * wb1.w + (o3 - sv.w) * wb2.w;
#pragma unroll
    for (int off = 8; off > 0; off >>= 1) gd += __shfl_xor(gd, off, 16);
    float g = 1.f / (1.f + __expf(-gd));
    float h0 = fmaxf(g * sv.x + (1.f - g) * o0, 0.f);
    float h1 = fmaxf(g * sv.y + (1.f - g) * o1, 0.f);
    float h2 = fmaxf(g * sv.z + (1.f - g) * o2, 0.f);
    float h3 = fmaxf(g * sv.w + (1.f - g) * o3, 0.f);
    float4 wcv = *(const float4*)(wc + c0);
    float t = h0 * wcv.x + h1 * wcv.y + h2 * wcv.z + h3 * wcv.w;
#pragma unroll
    for (int off = 8; off > 0; off >>= 1) t += __shfl_xor(t, off, 16);
    if (l16 == 0) OUT[grp] = t + bc[0];
}

extern "C" void kernel_launch(void* const* d_in, const int* in_sizes, int n_in,
                              void* d_out, int out_size, void* d_ws, size_t ws_size,
                              hipStream_t stream) {
    const float* x  = (const float*)d_in[0];
    const int*   ei = (const int*)d_in[1];
    const float* ea = (const float*)d_in[2];
    const int N = in_sizes[0] / 32;
    const int E = in_sizes[1] / 2;

    int p = 3;
    const float *wq1=(const float*)d_in[p+0], *bq1=(const float*)d_in[p+1],
                *wk1=(const float*)d_in[p+2], *bk1=(const float*)d_in[p+3],
                *wv1=(const float*)d_in[p+4], *bv1=(const float*)d_in[p+5],
                *we1=(const float*)d_in[p+6],
                *wsk1=(const float*)d_in[p+7], *bsk1=(const float*)d_in[p+8],
                *wb1=(const float*)d_in[p+9];
    p += 10;
    const float *wq2=(const float*)d_in[p+0], *bq2=(const float*)d_in[p+1],
                *wk2=(const float*)d_in[p+2], *bk2=(const float*)d_in[p+3],
                *wv2=(const float*)d_in[p+4], *bv2=(const float*)d_in[p+5],
                *we2=(const float*)d_in[p+6],
                *wsk2=(const float*)d_in[p+7], *bsk2=(const float*)d_in[p+8],
                *wb2=(const float*)d_in[p+9];
    p += 10;
    const float *wq3=(const float*)d_in[p+0], *bq3=(const float*)d_in[p+1],
                *wk3=(const float*)d_in[p+2], *bk3=(const float*)d_in[p+3],
                *wv3=(const float*)d_in[p+4], *bv3=(const float*)d_in[p+5],
                *we3=(const float*)d_in[p+6],
                *wsk3=(const float*)d_in[p+7], *bsk3=(const float*)d_in[p+8],
                *wb3=(const float*)d_in[p+9];
    p += 10;
    const float *wc = (const float*)d_in[p+0], *bc = (const float*)d_in[p+1];

    float* out = (float*)d_out;

    // workspace layout
    size_t NB = (size_t)N * 64;
    float* ws = (float*)d_ws;
    float* Hb = ws;
    float* Qb = Hb + NB;
    float* Kb = Qb + NB;
    float* Vb = Kb + NB;
    float* Sb = Vb + NB;
    int* ip      = (int*)(Sb + NB);
    int* rowptr  = ip;                 // N+1
    int* deg     = rowptr + (N + 2);   // N (also scatter cursor)
    int* bsum    = deg + N;            // 512
    int* boff    = bsum + 512;         // 512
    size_t ioff = (size_t)(N + 2 + N + 1024);
    ioff = (ioff + 1) & ~(size_t)1;    // 8B-align
    int2* rec    = (int2*)(ip + ioff); // E records

    const int BLK = 256;
    const int NBLK = (N + SCAN_BLK - 1) / SCAN_BLK;

    // ---------------- CSR build ----------------
    hipMemsetAsync(deg, 0, (size_t)N * sizeof(int), stream);
    count_kernel<<<(E + BLK - 1) / BLK, BLK, 0, stream>>>(ei, deg, E);
    scan1_kernel<<<NBLK, SCAN_BLK, 0, stream>>>(deg, rowptr, bsum, N);
    scan2_kernel<<<1, 512, 0, stream>>>(bsum, boff, NBLK);
    scan3_kernel<<<(N + BLK - 1) / BLK, BLK, 0, stream>>>(rowptr, boff, N, E);
    hipMemsetAsync(deg, 0, (size_t)N * sizeof(int), stream);
    scatter_kernel<<<(E + BLK - 1) / BLK, BLK, 0, stream>>>(ei, rowptr, deg, rec, E);

    // ------- layer 1: cin=32, H=8, C=6 (pad 8, HCP=64) -------
    proj_kernel<32,8,6,8><<<(N*48 + BLK-1)/BLK, BLK, 0, stream>>>(
        x, wq1,bq1, wk1,bk1, wv1,bv1, wsk1,bsk1, Qb,Kb,Vb,Sb, N);
    gather8f_kernel<6,8><<<(N*8 + BLK-1)/BLK, BLK, 0, stream>>>(
        rowptr, rec, ea, we1, Qb, Kb, Vb, Sb, wb1, Hb, N, 1.0f/sqrtf(6.0f));

    // ------- layer 2: cin=48, H=8, C=3 (pad 4, HCP=32) -------
    proj_kernel<48,8,3,4><<<(N*24 + BLK-1)/BLK, BLK, 0, stream>>>(
        Hb, wq2,bq2, wk2,bk2, wv2,bv2, wsk2,bsk2, Qb,Kb,Vb,Sb, N);
    gather8f_kernel<3,4><<<(N*8 + BLK-1)/BLK, BLK, 0, stream>>>(
        rowptr, rec, ea, we2, Qb, Kb, Vb, Sb, wb2, Hb, N, 1.0f/sqrtf(3.0f));

    // ------- layer 3: cin=24, H=1, C=64 -------
    proj_kernel<24,1,64,64><<<(N*64 + BLK-1)/BLK, BLK, 0, stream>>>(
        Hb, wq3,bq3, wk3,bk3, wv3,bv3, wsk3,bsk3, Qb,Kb,Vb,Sb, N);
    gather64f_kernel<<<((size_t)N*16 + BLK-1)/BLK, BLK, 0, stream>>>(
        rowptr, rec, ea, we3, Qb, Kb, Vb, Sb, wb3, wc, bc, out, N, 1.0f/8.0f);
}